// Round 11
// baseline (241709.424 us; speedup 1.0000x reference)
//
#include <hip/hip_runtime.h>
#include <cstdint>
#include <cstddef>

#define TINYF 1.17549435e-38f

__device__ __forceinline__ uint32_t rotl32(uint32_t x, int r){ return (x<<r)|(x>>(32-r)); }

// threefry2x32, 20 rounds (exact JAX schedule)
__device__ __forceinline__ void tf2x32(uint32_t k0, uint32_t k1, uint32_t x0, uint32_t x1,
                                       uint32_t& o0, uint32_t& o1){
  uint32_t k2 = k0 ^ k1 ^ 0x1BD11BDAu;
  x0 += k0; x1 += k1;
  x0 += x1; x1 = rotl32(x1,13); x1 ^= x0;
  x0 += x1; x1 = rotl32(x1,15); x1 ^= x0;
  x0 += x1; x1 = rotl32(x1,26); x1 ^= x0;
  x0 += x1; x1 = rotl32(x1, 6); x1 ^= x0;
  x0 += k1; x1 += k2 + 1u;
  x0 += x1; x1 = rotl32(x1,17); x1 ^= x0;
  x0 += x1; x1 = rotl32(x1,29); x1 ^= x0;
  x0 += x1; x1 = rotl32(x1,16); x1 ^= x0;
  x0 += x1; x1 = rotl32(x1,24); x1 ^= x0;
  x0 += k2; x1 += k0 + 2u;
  x0 += x1; x1 = rotl32(x1,13); x1 ^= x0;
  x0 += x1; x1 = rotl32(x1,15); x1 ^= x0;
  x0 += x1; x1 = rotl32(x1,26); x1 ^= x0;
  x0 += x1; x1 = rotl32(x1, 6); x1 ^= x0;
  x0 += k0; x1 += k1 + 3u;
  x0 += x1; x1 = rotl32(x1,17); x1 ^= x0;
  x0 += x1; x1 = rotl32(x1,29); x1 ^= x0;
  x0 += x1; x1 = rotl32(x1,16); x1 ^= x0;
  x0 += x1; x1 = rotl32(x1,24); x1 ^= x0;
  x0 += k1; x1 += k2 + 4u;
  x0 += x1; x1 = rotl32(x1,13); x1 ^= x0;
  x0 += x1; x1 = rotl32(x1,15); x1 ^= x0;
  x0 += x1; x1 = rotl32(x1,26); x1 ^= x0;
  x0 += x1; x1 = rotl32(x1, 6); x1 ^= x0;
  o0 = x0 + k2; o1 = x1 + k0 + 5u;
}

// 128x128-tile f32 GEMM for perm logits slab: C[512 rows x 32768] = A[512x512] @ Wperm.
// TM=TN=8, BK=16, 256 threads.
__global__ __launch_bounds__(256) void gemm_logits(
    const float* __restrict__ A, const float* __restrict__ Bw, float* __restrict__ C){
  __shared__ float As[16][132];
  __shared__ float Bs[16][132];
  const int tid = threadIdx.x;
  const long m0 = (long)blockIdx.y * 128;
  const long n0 = (long)blockIdx.x * 128;
  const int tx = tid & 15, ty = tid >> 4;
  const int r0 = ty * 8, c0 = tx * 8;
  float acc[8][8];
#pragma unroll
  for (int i=0;i<8;i++)
#pragma unroll
    for (int j=0;j<8;j++) acc[i][j]=0.f;

  const int arow = tid >> 2, akq = (tid & 3) * 4;   // A: 2 float4/thread (rows arow, arow+64)
  const int bkk = tid >> 4, bnq = (tid & 15) * 8;   // B: 2 float4/thread

#pragma unroll 1
  for (int k0=0;k0<512;k0+=16){
    {
      float4 v0 = *reinterpret_cast<const float4*>(&A[(m0+arow)*512 + k0 + akq]);
      float4 v1 = *reinterpret_cast<const float4*>(&A[(m0+arow+64)*512 + k0 + akq]);
      As[akq+0][arow] = v0.x; As[akq+1][arow] = v0.y; As[akq+2][arow] = v0.z; As[akq+3][arow] = v0.w;
      As[akq+0][arow+64] = v1.x; As[akq+1][arow+64] = v1.y; As[akq+2][arow+64] = v1.z; As[akq+3][arow+64] = v1.w;
      *reinterpret_cast<float4*>(&Bs[bkk][bnq]) =
        *reinterpret_cast<const float4*>(&Bw[(long)(k0+bkk)*32768 + n0 + bnq]);
      *reinterpret_cast<float4*>(&Bs[bkk][bnq+4]) =
        *reinterpret_cast<const float4*>(&Bw[(long)(k0+bkk)*32768 + n0 + bnq + 4]);
    }
    __syncthreads();
#pragma unroll
    for (int kk=0;kk<16;kk++){
      float a[8], b[8];
      *reinterpret_cast<float4*>(&a[0]) = *reinterpret_cast<const float4*>(&As[kk][r0]);
      *reinterpret_cast<float4*>(&a[4]) = *reinterpret_cast<const float4*>(&As[kk][r0+4]);
      *reinterpret_cast<float4*>(&b[0]) = *reinterpret_cast<const float4*>(&Bs[kk][c0]);
      *reinterpret_cast<float4*>(&b[4]) = *reinterpret_cast<const float4*>(&Bs[kk][c0+4]);
#pragma unroll
      for (int i=0;i<8;i++)
#pragma unroll
        for (int j=0;j<8;j++) acc[i][j] = fmaf(a[i], b[j], acc[i][j]);
    }
    __syncthreads();
  }
#pragma unroll 1
  for (int i=0;i<8;i++){
    *reinterpret_cast<float4*>(&C[(m0+r0+i)*32768 + n0 + c0])   = *reinterpret_cast<const float4*>(&acc[i][0]);
    *reinterpret_cast<float4*>(&C[(m0+r0+i)*32768 + n0 + c0+4]) = *reinterpret_cast<const float4*>(&acc[i][4]);
  }
}

// 256 threads = 4 waves = 4 heads; lane j = column; argmax_i(logit + gumbel), first max.
// V3 PRNG (verified round-10): partitionable counters (0, n), bits = o0 ^ o1.
__global__ __launch_bounds__(256) void perm_argmax(const float* __restrict__ L,
                                                   unsigned char* __restrict__ idx, int slab0){
  const int h = blockIdx.x*4 + (threadIdx.x >> 6);
  const int btl = blockIdx.y;
  const int bt = slab0 + btl;
  const int b = bt >> 11;
  const int t = bt & 2047;
  const int j = threadIdx.x & 63;
  uint32_t kk0, kk1;
  tf2x32(0u, 42u, 0u, (uint32_t)t, kk0, kk1);   // fold_in(key(42), t)
  const float* Lp = L + (size_t)btl*32768 + h*4096 + j;
  const int bh = b*8 + h;
  const uint32_t nbase = (uint32_t)bh*4096u + (uint32_t)j;
  float best = -INFINITY; int bi = 0;
#pragma unroll 1
  for (int i=0;i<64;i++){
    float logit = Lp[i*64];
    uint32_t o0, o1;
    tf2x32(kk0, kk1, 0u, nbase + (uint32_t)i*64u, o0, o1);
    uint32_t bits = o0 ^ o1;
    float f = __uint_as_float((bits>>9) | 0x3f800000u) - 1.0f;
    float u = fmaxf(TINYF, f + TINYF);
    float g = -logf(-logf(u));
    float val = logit + g;
    if (val > best){ best = val; bi = i; }
  }
  idx[(size_t)bt*512 + h*64 + j] = (unsigned char)bi;
}

// q/k/v projections, f32. z: 0=q(silu+l2), 1=k(silu+l2), 2=v(silu)
__global__ __launch_bounds__(256) void gemm_qkv(
    const float* __restrict__ A, const float* __restrict__ Wq, const float* __restrict__ Wk,
    const float* __restrict__ Wv, float* __restrict__ qb, float* __restrict__ kb,
    float* __restrict__ vb){
  const int z = blockIdx.z;
  const float* Bw = (z==0) ? Wq : ((z==1) ? Wk : Wv);
  float* C = (z==0) ? qb : ((z==1) ? kb : vb);
  __shared__ float As[16][132];
  __shared__ float Bs[16][68];
  const int tid = threadIdx.x;
  const long m0 = (long)blockIdx.y * 128;
  const long n0 = (long)blockIdx.x * 64;
  const int tx = tid & 15, ty = tid >> 4;
  const int r0 = ty * 8, c0 = tx * 4;
  float acc[8][4];
#pragma unroll
  for (int i=0;i<8;i++){ acc[i][0]=0.f; acc[i][1]=0.f; acc[i][2]=0.f; acc[i][3]=0.f; }
  const int arow = tid >> 2, akq = (tid & 3) * 4;
  const int bkk = tid >> 4, bnq = (tid & 15) * 4;
#pragma unroll 1
  for (int k0=0;k0<512;k0+=16){
    {
      float4 v0 = *reinterpret_cast<const float4*>(&A[(m0+arow)*512 + k0 + akq]);
      float4 v1 = *reinterpret_cast<const float4*>(&A[(m0+arow+64)*512 + k0 + akq]);
      As[akq+0][arow] = v0.x; As[akq+1][arow] = v0.y; As[akq+2][arow] = v0.z; As[akq+3][arow] = v0.w;
      As[akq+0][arow+64] = v1.x; As[akq+1][arow+64] = v1.y; As[akq+2][arow+64] = v1.z; As[akq+3][arow+64] = v1.w;
      *reinterpret_cast<float4*>(&Bs[bkk][bnq]) =
        *reinterpret_cast<const float4*>(&Bw[(long)(k0+bkk)*512 + n0 + bnq]);
    }
    __syncthreads();
#pragma unroll
    for (int kk=0;kk<16;kk++){
      float a[8], b[4];
      *reinterpret_cast<float4*>(&a[0]) = *reinterpret_cast<const float4*>(&As[kk][r0]);
      *reinterpret_cast<float4*>(&a[4]) = *reinterpret_cast<const float4*>(&As[kk][r0+4]);
      *reinterpret_cast<float4*>(&b[0]) = *reinterpret_cast<const float4*>(&Bs[kk][c0]);
#pragma unroll
      for (int i=0;i<8;i++){
        acc[i][0] = fmaf(a[i], b[0], acc[i][0]);
        acc[i][1] = fmaf(a[i], b[1], acc[i][1]);
        acc[i][2] = fmaf(a[i], b[2], acc[i][2]);
        acc[i][3] = fmaf(a[i], b[3], acc[i][3]);
      }
    }
    __syncthreads();
  }
#pragma unroll 1
  for (int i=0;i<8;i++){
#pragma unroll
    for (int j=0;j<4;j++){ float zz=acc[i][j]; acc[i][j] = zz/(1.f+expf(-zz)); }
    if (z != 2){   // q,k: per-head l2norm over the 64-col head block
      float s = acc[i][0]*acc[i][0] + acc[i][1]*acc[i][1] + acc[i][2]*acc[i][2] + acc[i][3]*acc[i][3];
      s += __shfl_xor(s,1); s += __shfl_xor(s,2); s += __shfl_xor(s,4); s += __shfl_xor(s,8);
      float sc = 1.f/(sqrtf(s)+1e-6f);
#pragma unroll
      for (int j=0;j<4;j++) acc[i][j]*=sc;
    }
    *reinterpret_cast<float4*>(&C[(m0+r0+i)*512 + n0 + c0]) = *reinterpret_cast<const float4*>(&acc[i][0]);
  }
}

// block = 4 waves, wave w handles row r; 8 head-dots of length 512
__global__ __launch_bounds__(256) void beta_sigmoid(const float* __restrict__ x,
                                                    const float* __restrict__ Wb,
                                                    float* __restrict__ beta){
  const int w = threadIdx.x >> 6, l = threadIdx.x & 63;
  const int r = blockIdx.x*4 + w;
  float a[8];
#pragma unroll
  for (int hh=0; hh<8; hh++) a[hh]=0.f;
  const float* xr = x + (size_t)r*512;
#pragma unroll 1
  for (int c=0;c<8;c++){
    float xv = xr[c*64 + l];
    const float* wrow = Wb + (size_t)(c*64+l)*8;
#pragma unroll
    for (int hh=0;hh<8;hh++) a[hh] = fmaf(xv, wrow[hh], a[hh]);
  }
#pragma unroll 1
  for (int hh=0;hh<8;hh++){
    float s = a[hh];
    s += __shfl_xor(s,1); s += __shfl_xor(s,2); s += __shfl_xor(s,4);
    s += __shfl_xor(s,8); s += __shfl_xor(s,16); s += __shfl_xor(s,32);
    if (l == hh) beta[(size_t)r*8 + hh] = 1.f/(1.f+expf(-s));
  }
}

// atomic-free recurrence, f32 state. Per-step P*M via SWAR byte-compare row masks
// (exact zero-byte detect, no cross-byte carries) + deterministic gather.
__global__ __launch_bounds__(256) void recurrence(
    const float* __restrict__ q, const float* __restrict__ k, const float* __restrict__ v,
    const float* __restrict__ beta, const unsigned char* __restrict__ idx,
    const int* __restrict__ mask, float* __restrict__ attn){
  constexpr int MS = 68;   // padded row stride (floats), 16B-aligned
  const int b = blockIdx.x >> 3, h = blockIdx.x & 7;
  __shared__ float M1[64*MS];
  __shared__ float M2[64*MS];
  __shared__ float qs[64], ks[64], vs[64], dl[64];
  __shared__ float part[4][64];
  __shared__ uint64_t ids64[8];
  const int tid = threadIdx.x;
  const int l6 = tid & 63, g6 = tid >> 6;
  for (int i = tid; i < 64*MS; i += 256) M1[i] = 0.f;
  __syncthreads();
#pragma unroll 1
  for (int t=0;t<2048;t++){
    const int bt = b*2048 + t;
    const size_t base = (size_t)bt*512 + (size_t)h*64;
    if (g6==0)      qs[l6] = q[base+l6];
    else if (g6==1) ks[l6] = k[base+l6];
    else if (g6==2) vs[l6] = v[base+l6];
    else            ((unsigned char*)ids64)[l6] = idx[(size_t)bt*512 + h*64 + l6];
    const float bval = beta[(size_t)bt*8+h] * (float)mask[bt];
    __syncthreads();
    // lane l6 owns output row l6: mymask bit j = (ids[j] == l6), built via SWAR
    uint64_t mymask = 0;
    {
      const uint64_t rep = 0x0101010101010101ull * (uint64_t)l6;
#pragma unroll
      for (int w=0;w<8;w++){
        uint64_t x = ids64[w] ^ rep;
        // exact zero-byte detector (carry-free): 0x80 at byte==0
        uint64_t y = (x & 0x7F7F7F7F7F7F7F7Full) + 0x7F7F7F7F7F7F7F7Full;
        uint64_t z = ~(y | x | 0x7F7F7F7F7F7F7F7Full);
        uint32_t m8 = (uint32_t)(((z >> 7) * 0x0102040810204080ull) >> 56);
        mymask |= (uint64_t)m8 << (w*8);
      }
    }
    // gather: M2[l6][g6*16 .. +16) = sum over set bits j of M1[j][...]
    float acc[16];
#pragma unroll
    for (int d=0;d<16;d++) acc[d]=0.f;
    uint64_t mm = mymask;
    const int dbase = g6*16;
#pragma unroll 1
    while (mm){
      const int j = __builtin_ctzll(mm); mm &= (mm-1);
      const float* src = &M1[j*MS + dbase];
#pragma unroll
      for (int d=0;d<16;d+=4){
        float4 vv = *reinterpret_cast<const float4*>(&src[d]);
        acc[d]+=vv.x; acc[d+1]+=vv.y; acc[d+2]+=vv.z; acc[d+3]+=vv.w;
      }
    }
#pragma unroll
    for (int d=0;d<16;d+=4)
      *reinterpret_cast<float4*>(&M2[l6*MS + dbase + d]) = make_float4(acc[d],acc[d+1],acc[d+2],acc[d+3]);
    __syncthreads();
    // out[d] = sum_r qs[r]*M2[r][d] ; delta[j] = vs[j] - sum_d M2[j][d]*ks[d]
    {
      float accO = 0.f;
#pragma unroll
      for (int hh=0; hh<16; hh++){
        const int r = g6*16 + hh;
        accO = fmaf(qs[r], M2[r*MS + l6], accO);
      }
      part[g6][l6] = accO;
      const int j = tid >> 2, qd = tid & 3;
      float accK = 0.f;
#pragma unroll
      for (int dd=0; dd<16; dd++){
        const int d2 = qd*16 + dd;
        accK = fmaf(M2[j*MS + d2], ks[d2], accK);
      }
      accK += __shfl_xor(accK,1); accK += __shfl_xor(accK,2);
      if (qd==0) dl[j] = vs[j] - accK;
    }
    __syncthreads();
    if (tid < 64) attn[base + tid] = part[0][tid]+part[1][tid]+part[2][tid]+part[3][tid];
    // M1 = M2 + bval*ks[row]*dl[col]
    {
      const int i = tid >> 2, cq = (tid & 3)*16;
      const float bk = bval * ks[i];
#pragma unroll
      for (int c4=0;c4<4;c4++){
        float4 m2v = *reinterpret_cast<const float4*>(&M2[i*MS + cq + c4*4]);
        float4 dv  = *reinterpret_cast<const float4*>(&dl[cq + c4*4]);
        float4 r;
        r.x = fmaf(bk, dv.x, m2v.x); r.y = fmaf(bk, dv.y, m2v.y);
        r.z = fmaf(bk, dv.z, m2v.z); r.w = fmaf(bk, dv.w, m2v.w);
        *reinterpret_cast<float4*>(&M1[i*MS + cq + c4*4]) = r;
      }
    }
    __syncthreads();
  }
}

// Wo GEMM with fused RMS-norm (f32): ssum during A staging, rms_w folded into As,
// 1/rms applied in epilogue ( (x/rms*w)@Wo == ((x*w)@Wo)/rms per row ).
__global__ __launch_bounds__(256) void gemm_rms(
    const float* __restrict__ A, const float* __restrict__ rw,
    const float* __restrict__ Bw, float* __restrict__ C){
  __shared__ float As[16][132];
  __shared__ float Bs[16][68];
  __shared__ float scl[128];
  const int tid = threadIdx.x;
  const long m0 = (long)blockIdx.y * 128;
  const long n0 = (long)blockIdx.x * 64;
  const int tx = tid & 15, ty = tid >> 4;
  const int r0 = ty * 8, c0 = tx * 4;
  float acc[8][4];
#pragma unroll
  for (int i=0;i<8;i++){ acc[i][0]=0.f; acc[i][1]=0.f; acc[i][2]=0.f; acc[i][3]=0.f; }
  const int arow = tid >> 2, akq = (tid & 3) * 4;
  const int bkk = tid >> 4, bnq = (tid & 15) * 4;
  float ss0 = 0.f, ss1 = 0.f;
#pragma unroll 1
  for (int k0=0;k0<512;k0+=16){
    {
      float4 v0 = *reinterpret_cast<const float4*>(&A[(m0+arow)*512 + k0 + akq]);
      float4 v1 = *reinterpret_cast<const float4*>(&A[(m0+arow+64)*512 + k0 + akq]);
      float4 w4 = *reinterpret_cast<const float4*>(&rw[k0 + akq]);
      ss0 += v0.x*v0.x + v0.y*v0.y + v0.z*v0.z + v0.w*v0.w;
      ss1 += v1.x*v1.x + v1.y*v1.y + v1.z*v1.z + v1.w*v1.w;
      As[akq+0][arow] = v0.x*w4.x; As[akq+1][arow] = v0.y*w4.y;
      As[akq+2][arow] = v0.z*w4.z; As[akq+3][arow] = v0.w*w4.w;
      As[akq+0][arow+64] = v1.x*w4.x; As[akq+1][arow+64] = v1.y*w4.y;
      As[akq+2][arow+64] = v1.z*w4.z; As[akq+3][arow+64] = v1.w*w4.w;
      *reinterpret_cast<float4*>(&Bs[bkk][bnq]) =
        *reinterpret_cast<const float4*>(&Bw[(long)(k0+bkk)*512 + n0 + bnq]);
    }
    __syncthreads();
#pragma unroll
    for (int kk=0;kk<16;kk++){
      float a[8], b[4];
      *reinterpret_cast<float4*>(&a[0]) = *reinterpret_cast<const float4*>(&As[kk][r0]);
      *reinterpret_cast<float4*>(&a[4]) = *reinterpret_cast<const float4*>(&As[kk][r0+4]);
      *reinterpret_cast<float4*>(&b[0]) = *reinterpret_cast<const float4*>(&Bs[kk][c0]);
#pragma unroll
      for (int i=0;i<8;i++){
        acc[i][0] = fmaf(a[i], b[0], acc[i][0]);
        acc[i][1] = fmaf(a[i], b[1], acc[i][1]);
        acc[i][2] = fmaf(a[i], b[2], acc[i][2]);
        acc[i][3] = fmaf(a[i], b[3], acc[i][3]);
      }
    }
    __syncthreads();
  }
  ss0 += __shfl_xor(ss0,1); ss0 += __shfl_xor(ss0,2);
  ss1 += __shfl_xor(ss1,1); ss1 += __shfl_xor(ss1,2);
  if ((tid & 3) == 0){
    scl[arow]    = 1.f/sqrtf(ss0*(1.f/512.f) + 1e-6f);
    scl[arow+64] = 1.f/sqrtf(ss1*(1.f/512.f) + 1e-6f);
  }
  __syncthreads();
#pragma unroll 1
  for (int i=0;i<8;i++){
    const float sc = scl[r0+i];
#pragma unroll
    for (int j=0;j<4;j++) acc[i][j] *= sc;
    *reinterpret_cast<float4*>(&C[(m0+r0+i)*512 + n0 + c0]) = *reinterpret_cast<const float4*>(&acc[i][0]);
  }
}

extern "C" void kernel_launch(void* const* d_in, const int* in_sizes, int n_in,
                              void* d_out, int out_size, void* d_ws, size_t ws_size,
                              hipStream_t stream){
  const float* x     = (const float*)d_in[0];
  const float* Wq    = (const float*)d_in[1];
  const float* Wk    = (const float*)d_in[2];
  const float* Wv    = (const float*)d_in[3];
  const float* Wo    = (const float*)d_in[4];
  const float* Wbeta = (const float*)d_in[5];
  const float* Wperm = (const float*)d_in[6];
  const float* rmsw  = (const float*)d_in[7];
  const int*   mask  = (const int*)d_in[8];
  float* out = (float*)d_out;

  char* ws = (char*)d_ws;
  const size_t QB    = 33554432ull;    // 16384*512*4 bytes
  const size_t BETAB = 524288ull;      // 16384*8*4
  // layout (105.4 MB, proven bound): kb | vb | qb | betab | idxb
  float* kb    = (float*)ws;
  float* vb    = (float*)(ws + QB);
  float* qb    = (float*)(ws + 2*QB);
  float* betab = (float*)(ws + 3*QB);
  unsigned char* idxb = (unsigned char*)(ws + 3*QB + BETAB);
  float* slab  = kb;    // kb|vb contiguous: 64 MB = 512 logits rows (dead until phase 2)

  dim3 blk(256);
  // Phase 1: perm logits (512-row slab) + gumbel argmax -> idxb. 32 iters.
  for (int s0 = 0; s0 < 16384; s0 += 512){
    gemm_logits<<<dim3(256,4),blk,0,stream>>>(x + (size_t)s0*512, Wperm, slab);
    perm_argmax<<<dim3(2,512),blk,0,stream>>>(slab, idxb, s0);
  }
  // Phase 2: q/k/v projections (one dispatch; k,v overwrite slab) + beta
  gemm_qkv<<<dim3(8,128,3),blk,0,stream>>>(x, Wq, Wk, Wv, qb, kb, vb);
  beta_sigmoid<<<4096,blk,0,stream>>>(x, Wbeta, betab);
  // Phase 3: sequential delta-rule recurrence, q->attn in place in qb
  recurrence<<<64,blk,0,stream>>>(qb, kb, vb, betab, idxb, mask, qb);
  // Phase 4: fused RMS-norm + Wo projection -> d_out
  gemm_rms<<<dim3(8,128),blk,0,stream>>>(qb, rmsw, Wo, out);
}